// Round 8
// baseline (268.267 us; speedup 1.0000x reference)
//
#include <hip/hip_runtime.h>
#include <math.h>

#define T_ 4096
#define D_ 128
#define NTOK 8192
#define CHUNK 64
#define NCB 64        // chunks per batch
#define NCH 128       // total chunks
#define NBLK 512
#define LN_EPS 1e-5f
#define EPS_ATTN 1e-6f

typedef __attribute__((ext_vector_type(8))) short bf16x8;
typedef __attribute__((ext_vector_type(4))) short bf16x4;
typedef __attribute__((ext_vector_type(4))) float f32x4;

__device__ inline short f2bf(float f) {
  unsigned u = __builtin_bit_cast(unsigned, f);
  u += 0x7fffu + ((u >> 16) & 1u);
  return (short)(u >> 16);
}
__device__ inline float bf2f(short s) {
  unsigned u = ((unsigned)(unsigned short)s) << 16;
  return __builtin_bit_cast(float, u);
}
__device__ inline float phi_(float x) { return x > 0.f ? x + 1.f : __expf(x); }

// one-shot grid barrier (counters pre-zeroed by hipMemsetAsync).
// Arrival: one release-RMW per block; poll: relaxed atomic LOADS (no RMW
// serialization) + s_sleep; acquire fence after. All 512 blocks co-resident:
// LDS ~53KB -> 2+ blocks/CU (needs <80KB), VGPR 2 waves/SIMD*<=256 <= 512.
__device__ inline void gbar(unsigned* cnt) {
  __syncthreads();
  if (threadIdx.x == 0) {
    __hip_atomic_fetch_add(cnt, 1u, __ATOMIC_RELEASE, __HIP_MEMORY_SCOPE_AGENT);
    while (__hip_atomic_load(cnt, __ATOMIC_RELAXED, __HIP_MEMORY_SCOPE_AGENT) < NBLK)
      __builtin_amdgcn_s_sleep(16);
    __builtin_amdgcn_fence(__ATOMIC_ACQUIRE, "agent");
  }
  __syncthreads();
}

struct Params {
  const float *tokens, *Wq, *Wk, *Wv, *Wg, *bg, *Wo, *g1, *b1, *g2, *b2;
  short *Qp, *Kp, *KpT, *VgT, *attn, *KVTb;
  float *KVT, *Ksum, *out;
  unsigned *bar;
};

struct S1 { short xs[64][136]; short wsd[128][136]; };
struct S2 { short vgl[64][72]; short kpl[64][72]; float ksp[64][5]; };
struct S4 { short at[64][200]; short bt[64][200];
            float ksl[128]; float rsl[64]; float dpart[64][4]; float denl[64]; };
struct S5 { short al[16][136]; short wl[128][136]; float tl[16][132];
            float suml[16][4]; float ssql[16][4]; float meanl[16]; float rstdl[16];
            float gl[128]; float bl2[128]; };

__global__ __launch_bounds__(256, 1) void mega(Params P) {
  __shared__ union { S1 s1; S2 s2; S4 s4; S5 s5; } sm;
  const int tid = threadIdx.x;
  const int bid = blockIdx.x;
  const int gsz = gridDim.x;
  const int w = tid >> 6, l = tid & 63, i = l & 15, q = l >> 4;

  // ---- LN1 of one 64-token tile -> xs (bf16), recomputed per consumer block ----
  auto ln1_tile = [&](int m0) {
    const int half = l >> 5;
    const int c4 = (l & 31) * 4;
    const float4 gg = *(const float4*)&P.g1[c4];
    const float4 bb = *(const float4*)&P.b1[c4];
    #pragma unroll
    for (int it = 0; it < 8; ++it) {
      const int t = w*16 + it*2 + half;
      const float4 v = *(const float4*)&P.tokens[(m0+t)*D_ + c4];
      float s = v.x+v.y+v.z+v.w;
      float qq = v.x*v.x+v.y*v.y+v.z*v.z+v.w*v.w;
      #pragma unroll
      for (int off = 1; off < 32; off <<= 1) {
        s += __shfl_xor(s, off); qq += __shfl_xor(qq, off);
      }
      const float mean = s*(1.f/D_);
      const float r2 = rsqrtf(qq*(1.f/D_) - mean*mean + LN_EPS);
      bf16x4 o;
      o.x = f2bf((v.x-mean)*r2*gg.x + bb.x);
      o.y = f2bf((v.y-mean)*r2*gg.y + bb.y);
      o.z = f2bf((v.z-mean)*r2*gg.z + bb.z);
      o.w = f2bf((v.w-mean)*r2*gg.w + bb.w);
      *(bf16x4*)&sm.s1.xs[t][c4] = o;
    }
  };

  // ================= stage 1: QKVG GEMMs (LN1 + W^T inline) ==========
  for (int u = bid; u < 512; u += gsz) {
    if (u < 256) {
      // (y, tile): full-width GEMM vs Wq or Wk
      const int y = u >> 7, p = u & 127;
      const int m0 = p * 64;
      const float* W = y ? P.Wk : P.Wq;
      #pragma unroll
      for (int it = 0; it < 16; ++it) {      // W^T fp32->bf16: wsd[n][k]
        const int f = it*1024 + tid*4;
        const int k = f >> 7, n = f & 127;
        const float4 v = *(const float4*)&W[f];
        sm.s1.wsd[n  ][k] = f2bf(v.x);
        sm.s1.wsd[n+1][k] = f2bf(v.y);
        sm.s1.wsd[n+2][k] = f2bf(v.z);
        sm.s1.wsd[n+3][k] = f2bf(v.w);
      }
      ln1_tile(m0);
      __syncthreads();
      f32x4 acc[4][2];
      #pragma unroll
      for (int mt = 0; mt < 4; ++mt)
        #pragma unroll
        for (int nt = 0; nt < 2; ++nt) acc[mt][nt] = (f32x4){0.f,0.f,0.f,0.f};
      #pragma unroll
      for (int kk = 0; kk < 4; ++kk) {
        bf16x8 a[4], bfr[2];
        #pragma unroll
        for (int mt = 0; mt < 4; ++mt) a[mt] = *(const bf16x8*)&sm.s1.xs[mt*16+i][kk*32+q*8];
        #pragma unroll
        for (int nt = 0; nt < 2; ++nt) bfr[nt] = *(const bf16x8*)&sm.s1.wsd[w*32+nt*16+i][kk*32+q*8];
        #pragma unroll
        for (int mt = 0; mt < 4; ++mt)
          #pragma unroll
          for (int nt = 0; nt < 2; ++nt)
            acc[mt][nt] = __builtin_amdgcn_mfma_f32_16x16x32_bf16(a[mt], bfr[nt], acc[mt][nt], 0, 0, 0);
      }
      if (y == 0) {
        #pragma unroll
        for (int mt = 0; mt < 4; ++mt)
          #pragma unroll
          for (int nt = 0; nt < 2; ++nt) {
            const int h = w*32 + nt*16 + i;
            #pragma unroll
            for (int r = 0; r < 4; ++r)
              P.Qp[(m0 + mt*16 + 4*q + r)*D_ + h] = f2bf(phi_(acc[mt][nt][r]));
          }
      } else {
        #pragma unroll
        for (int mt = 0; mt < 4; ++mt)
          #pragma unroll
          for (int nt = 0; nt < 2; ++nt) {
            const int h = w*32 + nt*16 + i;
            const int t0 = m0 + mt*16 + 4*q;
            bf16x4 o;
            #pragma unroll
            for (int r = 0; r < 4; ++r) {
              const short bv = f2bf(phi_(acc[mt][nt][r]));
              P.Kp[(t0+r)*D_ + h] = bv;
              o[r] = bv;
            }
            *(bf16x4*)&P.KpT[h*NTOK + t0] = o;
          }
      }
    } else {
      // (tile, n-half): Vg = (x@Wv)*sigmoid(x@Wg+bg) for 64 output cols
      const int v2 = u - 256;
      const int p = v2 >> 1, nh = v2 & 1;
      const int m0 = p * 64;
      #pragma unroll
      for (int it = 0; it < 8; ++it) {       // Wv half -> wsd rows 0..63
        const int f = it*1024 + tid*4;
        const int k = f >> 6, nn = f & 63;
        const float4 v = *(const float4*)&P.Wv[k*D_ + nh*64 + nn];
        sm.s1.wsd[nn  ][k] = f2bf(v.x);
        sm.s1.wsd[nn+1][k] = f2bf(v.y);
        sm.s1.wsd[nn+2][k] = f2bf(v.z);
        sm.s1.wsd[nn+3][k] = f2bf(v.w);
      }
      #pragma unroll
      for (int it = 0; it < 8; ++it) {       // Wg half -> wsd rows 64..127
        const int f = it*1024 + tid*4;
        const int k = f >> 6, nn = f & 63;
        const float4 v = *(const float4*)&P.Wg[k*D_ + nh*64 + nn];
        sm.s1.wsd[64+nn  ][k] = f2bf(v.x);
        sm.s1.wsd[64+nn+1][k] = f2bf(v.y);
        sm.s1.wsd[64+nn+2][k] = f2bf(v.z);
        sm.s1.wsd[64+nn+3][k] = f2bf(v.w);
      }
      ln1_tile(m0);
      __syncthreads();
      f32x4 accv[4], accg[4];
      #pragma unroll
      for (int mt = 0; mt < 4; ++mt) { accv[mt] = (f32x4){0.f,0.f,0.f,0.f}; accg[mt] = (f32x4){0.f,0.f,0.f,0.f}; }
      #pragma unroll
      for (int kk = 0; kk < 4; ++kk) {
        bf16x8 a[4];
        #pragma unroll
        for (int mt = 0; mt < 4; ++mt) a[mt] = *(const bf16x8*)&sm.s1.xs[mt*16+i][kk*32+q*8];
        bf16x8 bv = *(const bf16x8*)&sm.s1.wsd[w*16+i][kk*32+q*8];
        bf16x8 bgr = *(const bf16x8*)&sm.s1.wsd[64+w*16+i][kk*32+q*8];
        #pragma unroll
        for (int mt = 0; mt < 4; ++mt) {
          accv[mt] = __builtin_amdgcn_mfma_f32_16x16x32_bf16(a[mt], bv, accv[mt], 0, 0, 0);
          accg[mt] = __builtin_amdgcn_mfma_f32_16x16x32_bf16(a[mt], bgr, accg[mt], 0, 0, 0);
        }
      }
      const int h = nh*64 + w*16 + i;
      const float bgd = P.bg[h];
      #pragma unroll
      for (int mt = 0; mt < 4; ++mt) {
        const int t0 = m0 + mt*16 + 4*q;
        bf16x4 o;
        #pragma unroll
        for (int r = 0; r < 4; ++r) {
          const float gv = 1.f/(1.f + __expf(-(accg[mt][r] + bgd)));
          o[r] = f2bf(accv[mt][r] * gv);
        }
        *(bf16x4*)&P.VgT[h*NTOK + t0] = o;
      }
    }
  }
  gbar(P.bar + 0);

  // ================= stage 2: per-chunk KV^T quarter + Ksum ==========
  for (int u = bid; u < 512; u += gsz) {
    const int c = u >> 2, dh2 = (u >> 1) & 1, hh2 = u & 1;
    const int tb = c*CHUNK;
    for (int v = tid; v < 512; v += 256) {
      const int dd = v >> 3, c8 = (v & 7)*8;
      *(bf16x8*)&sm.s2.vgl[dd][c8] = *(const bf16x8*)&P.VgT[(dh2*64+dd)*NTOK + tb + c8];
      *(bf16x8*)&sm.s2.kpl[dd][c8] = *(const bf16x8*)&P.KpT[(hh2*64+dd)*NTOK + tb + c8];
    }
    __syncthreads();
    f32x4 acc[4];
    #pragma unroll
    for (int nt = 0; nt < 4; ++nt) acc[nt] = (f32x4){0.f,0.f,0.f,0.f};
    #pragma unroll
    for (int kk = 0; kk < 2; ++kk) {
      bf16x8 a = *(const bf16x8*)&sm.s2.vgl[w*16+i][kk*32+q*8];
      #pragma unroll
      for (int nt = 0; nt < 4; ++nt) {
        bf16x8 bb = *(const bf16x8*)&sm.s2.kpl[nt*16+i][kk*32+q*8];
        acc[nt] = __builtin_amdgcn_mfma_f32_16x16x32_bf16(a, bb, acc[nt], 0, 0, 0);
      }
    }
    float* KVc = P.KVT + (size_t)c*16384;
    #pragma unroll
    for (int nt = 0; nt < 4; ++nt)
      #pragma unroll
      for (int r = 0; r < 4; ++r) {
        const int d = dh2*64 + w*16 + 4*q + r;
        const int h = hh2*64 + nt*16 + i;
        KVc[d*D_ + h] = acc[nt][r];
      }
    if (dh2 == 0) {
      const int h = tid >> 2, part = tid & 3;
      float s = 0.f;
      #pragma unroll
      for (int t = 0; t < 16; ++t) s += bf2f(sm.s2.kpl[h][part*16 + t]);
      sm.s2.ksp[h][part] = s;
      __syncthreads();
      if (tid < 64)
        P.Ksum[c*D_ + hh2*64 + tid] = sm.s2.ksp[tid][0]+sm.s2.ksp[tid][1]+sm.s2.ksp[tid][2]+sm.s2.ksp[tid][3];
    }
  }
  gbar(P.bar + 1);

  // ================= stage 3: exclusive chunk prefix ==========
  for (int u = bid; u < 129; u += gsz) {
    if (u < 128) {
      const int b = u >> 6;
      const int e = (u & 63)*256 + tid;
      const size_t base = (size_t)b*NCB*16384 + e;
      float run = 0.f;
      #pragma unroll 8
      for (int c = 0; c < NCB; ++c) {
        const float v = P.KVT[base + (size_t)c*16384];
        P.KVTb[base + (size_t)c*16384] = f2bf(run);
        run += v;
      }
    } else {
      const int b = tid >> 7, h = tid & 127;
      float run = 0.f;
      #pragma unroll 8
      for (int c = 0; c < NCB; ++c) {
        const int idx = (b*NCB + c)*D_ + h;
        const float v = P.Ksum[idx];
        P.Ksum[idx] = run;
        run += v;
      }
    }
  }
  gbar(P.bar + 2);

  // ================= stage 4: scores + attnout (d-quarter) ==========
  for (int u = bid; u < 512; u += gsz) {
    const int c = u >> 2, dq = u & 3;
    const int tb = c*CHUNK;
    for (int v = tid; v < 1024; v += 256) {
      const int t = v >> 4, c8 = (v & 15)*8;
      *(bf16x8*)&sm.s4.at[t][64 + c8] = *(const bf16x8*)&P.Qp[(tb+t)*D_ + c8];
      *(bf16x8*)&sm.s4.bt[t][c8]      = *(const bf16x8*)&P.Kp[(tb+t)*D_ + c8];
    }
    if (tid < 128) sm.s4.ksl[tid] = P.Ksum[c*D_ + tid];
    __syncthreads();
    {
      f32x4 acc[4];
      #pragma unroll
      for (int nt = 0; nt < 4; ++nt) acc[nt] = (f32x4){0.f,0.f,0.f,0.f};
      #pragma unroll
      for (int kk = 0; kk < 4; ++kk) {
        bf16x8 a = *(const bf16x8*)&sm.s4.at[w*16+i][64 + kk*32+q*8];
        for (int nt = 0; nt <= w; ++nt) {
          bf16x8 bb = *(const bf16x8*)&sm.s4.bt[nt*16+i][kk*32+q*8];
          acc[nt] = __builtin_amdgcn_mfma_f32_16x16x32_bf16(a, bb, acc[nt], 0, 0, 0);
        }
      }
      float rs[4] = {0.f,0.f,0.f,0.f};
      #pragma unroll
      for (int nt = 0; nt < 4; ++nt)
        #pragma unroll
        for (int r = 0; r < 4; ++r) {
          const int t = w*16 + 4*q + r;
          const int s = nt*16 + i;
          const float v = (nt <= w && s <= t) ? acc[nt][r] : 0.f;
          rs[r] += v;
          sm.s4.at[t][s] = f2bf(v);
        }
      #pragma unroll
      for (int r = 0; r < 4; ++r) {
        #pragma unroll
        for (int off = 1; off < 16; off <<= 1) rs[r] += __shfl_xor(rs[r], off);
      }
      if (i == 0) {
        #pragma unroll
        for (int r = 0; r < 4; ++r) sm.s4.rsl[w*16 + 4*q + r] = rs[r];
      }
    }
    {
      const int t = tid >> 2, part = tid & 3;
      float dot = 0.f;
      #pragma unroll
      for (int h = 0; h < 32; ++h)
        dot += bf2f(sm.s4.at[t][64 + part*32 + h]) * sm.s4.ksl[part*32 + h];
      sm.s4.dpart[t][part] = dot;
    }
    __syncthreads();
    if (tid < 64)
      sm.s4.denl[tid] = fmaxf(sm.s4.rsl[tid] + sm.s4.dpart[tid][0]+sm.s4.dpart[tid][1]
                              +sm.s4.dpart[tid][2]+sm.s4.dpart[tid][3], EPS_ATTN);
    // restage bt rows 0..31: Vg d-quarter (cols 0:64) + KV_prev d-quarter (cols 64:192)
    for (int v = tid; v < 256; v += 256) {
      const int dd = v >> 3, c8 = (v & 7)*8;
      *(bf16x8*)&sm.s4.bt[dd][c8] = *(const bf16x8*)&P.VgT[(dq*32+dd)*NTOK + tb + c8];
    }
    for (int v = tid; v < 512; v += 256) {
      const int dd = v >> 4, c8 = (v & 15)*8;
      *(bf16x8*)&sm.s4.bt[dd][64 + c8] = *(const bf16x8*)&P.KVTb[(size_t)c*16384 + (dq*32+dd)*D_ + c8];
    }
    __syncthreads();
    f32x4 acc2[2];
    #pragma unroll
    for (int nt = 0; nt < 2; ++nt) acc2[nt] = (f32x4){0.f,0.f,0.f,0.f};
    #pragma unroll
    for (int kk = 0; kk < 6; ++kk) {
      bf16x8 a = *(const bf16x8*)&sm.s4.at[w*16+i][kk*32+q*8];
      #pragma unroll
      for (int nt = 0; nt < 2; ++nt) {
        bf16x8 bb = *(const bf16x8*)&sm.s4.bt[nt*16+i][kk*32+q*8];
        acc2[nt] = __builtin_amdgcn_mfma_f32_16x16x32_bf16(a, bb, acc2[nt], 0, 0, 0);
      }
    }
    #pragma unroll
    for (int r = 0; r < 4; ++r) {
      const int t = w*16 + 4*q + r;
      const float inv = 1.f / sm.s4.denl[t];
      #pragma unroll
      for (int nt = 0; nt < 2; ++nt)
        P.attn[(size_t)(tb+t)*D_ + dq*32 + nt*16 + i] = f2bf(acc2[nt][r] * inv);
    }
  }
  gbar(P.bar + 3);

  // ================= stage 5: out = LN2(tokens + 0.1*(attn@Wo)), 16-token tiles ==========
  for (int u = bid; u < 512; u += gsz) {
    const int m0 = u*16;
    for (int v = tid; v < 256; v += 256) {
      const int t = v >> 4, c8 = (v & 15)*8;
      *(bf16x8*)&sm.s5.al[t][c8] = *(const bf16x8*)&P.attn[(m0+t)*D_ + c8];
    }
    #pragma unroll
    for (int it = 0; it < 16; ++it) {        // Wo^T fp32->bf16
      const int f = it*1024 + tid*4;
      const int k = f >> 7, n = f & 127;
      const float4 v = *(const float4*)&P.Wo[f];
      sm.s5.wl[n  ][k] = f2bf(v.x);
      sm.s5.wl[n+1][k] = f2bf(v.y);
      sm.s5.wl[n+2][k] = f2bf(v.z);
      sm.s5.wl[n+3][k] = f2bf(v.w);
    }
    for (int v = tid; v < 512; v += 256) {
      const int t = v >> 5, c4 = (v & 31)*4;
      *(float4*)&sm.s5.tl[t][c4] = *(const float4*)&P.tokens[(m0+t)*D_ + c4];
    }
    if (tid < 128) { sm.s5.gl[tid] = P.g2[tid]; sm.s5.bl2[tid] = P.b2[tid]; }
    __syncthreads();
    f32x4 acc[2];
    #pragma unroll
    for (int j = 0; j < 2; ++j) acc[j] = (f32x4){0.f,0.f,0.f,0.f};
    #pragma unroll
    for (int kk = 0; kk < 4; ++kk) {
      bf16x8 a = *(const bf16x8*)&sm.s5.al[i][kk*32+q*8];
      #pragma unroll
      for (int j = 0; j < 2; ++j) {
        bf16x8 bb = *(const bf16x8*)&sm.s5.wl[(w*2+j)*16+i][kk*32+q*8];
        acc[j] = __builtin_amdgcn_mfma_f32_16x16x32_bf16(a, bb, acc[j], 0, 0, 0);
      }
    }
    float p[4][2], ps[4], qs[4];
    #pragma unroll
    for (int r = 0; r < 4; ++r) {
      const int t = 4*q + r;
      ps[r] = 0.f; qs[r] = 0.f;
      #pragma unroll
      for (int j = 0; j < 2; ++j) {
        const int col = w*32 + j*16 + i;
        const float v = sm.s5.tl[t][col] + 0.1f*acc[j][r];
        p[r][j] = v; ps[r] += v; qs[r] += v*v;
      }
    }
    #pragma unroll
    for (int r = 0; r < 4; ++r) {
      #pragma unroll
      for (int off = 1; off < 16; off <<= 1) {
        ps[r] += __shfl_xor(ps[r], off);
        qs[r] += __shfl_xor(qs[r], off);
      }
    }
    if (i == 0) {
      #pragma unroll
      for (int r = 0; r < 4; ++r) {
        sm.s5.suml[4*q+r][w] = ps[r];
        sm.s5.ssql[4*q+r][w] = qs[r];
      }
    }
    __syncthreads();
    if (tid < 16) {
      const float s = sm.s5.suml[tid][0]+sm.s5.suml[tid][1]+sm.s5.suml[tid][2]+sm.s5.suml[tid][3];
      const float qq = sm.s5.ssql[tid][0]+sm.s5.ssql[tid][1]+sm.s5.ssql[tid][2]+sm.s5.ssql[tid][3];
      const float mean = s*(1.f/D_);
      sm.s5.meanl[tid] = mean;
      sm.s5.rstdl[tid] = rsqrtf(qq*(1.f/D_) - mean*mean + LN_EPS);
    }
    __syncthreads();
    #pragma unroll
    for (int r = 0; r < 4; ++r) {
      const int t = 4*q + r;
      const float mean = sm.s5.meanl[t], rr = sm.s5.rstdl[t];
      #pragma unroll
      for (int j = 0; j < 2; ++j) {
        const int col = w*32 + j*16 + i;
        P.out[(m0+t)*D_ + col] = (p[r][j]-mean)*rr*sm.s5.gl[col] + sm.s5.bl2[col];
      }
    }
    __syncthreads();
  }
}

extern "C" void kernel_launch(void* const* d_in, const int* in_sizes, int n_in,
                              void* d_out, int out_size, void* d_ws, size_t ws_size,
                              hipStream_t stream) {
  char* base = (char*)d_ws;
  Params P;
  P.tokens = (const float*)d_in[0];
  P.Wq = (const float*)d_in[1];  P.Wk = (const float*)d_in[2];
  P.Wv = (const float*)d_in[3];  P.Wg = (const float*)d_in[4];
  P.bg = (const float*)d_in[5];  P.Wo = (const float*)d_in[6];
  P.g1 = (const float*)d_in[7];  P.b1 = (const float*)d_in[8];
  P.g2 = (const float*)d_in[9];  P.b2 = (const float*)d_in[10];
  P.Qp   = (short*)(base);                 // 2MB
  P.Kp   = (short*)(base + (2u<<20));      // 2MB
  P.KpT  = (short*)(base + (4u<<20));      // 2MB
  P.VgT  = (short*)(base + (6u<<20));      // 2MB
  P.attn = (short*)(base + (8u<<20));      // 2MB
  P.KVTb = (short*)(base + (10u<<20));     // 4MB
  P.KVT  = (float*)(base + (16u<<20));     // 8MB
  P.Ksum = (float*)(base + (24u<<20));     // 64KB
  P.bar  = (unsigned*)(base + (24u<<20) + (128u<<10));
  P.out  = (float*)d_out;

  hipMemsetAsync(P.bar, 0, 8*sizeof(unsigned), stream);
  mega<<<dim3(NBLK), dim3(256), 0, stream>>>(P);
}

// Round 9
// 116.739 us; speedup vs baseline: 2.2980x; 2.2980x over previous
//
#include <hip/hip_runtime.h>
#include <math.h>

#define T_ 4096
#define D_ 128
#define NTOK 8192
#define CHUNK 64
#define NCB 64        // chunks per batch
#define NCH 128       // total chunks
#define LN_EPS 1e-5f
#define EPS_ATTN 1e-6f

typedef __attribute__((ext_vector_type(8))) short bf16x8;
typedef __attribute__((ext_vector_type(4))) short bf16x4;
typedef __attribute__((ext_vector_type(4))) float f32x4;

__device__ inline short f2bf(float f) {
  unsigned u = __builtin_bit_cast(unsigned, f);
  u += 0x7fffu + ((u >> 16) & 1u);
  return (short)(u >> 16);
}
__device__ inline float bf2f(short s) {
  unsigned u = ((unsigned)(unsigned short)s) << 16;
  return __builtin_bit_cast(float, u);
}
__device__ inline float phi_(float x) { return x > 0.f ? x + 1.f : __expf(x); }

// ============ K0: weights fp32 [k][n] -> bf16 [n][k] once (5 mats) ============
// Padded fp32 LDS tile -> conflict-free transpose (verified R3).
__global__ __launch_bounds__(256) void k_wprep(const float* __restrict__ Wq,
    const float* __restrict__ Wk, const float* __restrict__ Wv,
    const float* __restrict__ Wg, const float* __restrict__ Wo,
    short* __restrict__ WT) {
  const float* W = blockIdx.x==0?Wq: blockIdx.x==1?Wk: blockIdx.x==2?Wv: blockIdx.x==3?Wg:Wo;
  short* out = WT + blockIdx.x*D_*D_;
  __shared__ float lds[128][132];
  const int tid = threadIdx.x;
  #pragma unroll
  for (int it = 0; it < 16; ++it) {
    const int f = it*1024 + tid*4;
    const int k = f >> 7, n = f & 127;
    const float4 v = *(const float4*)&W[f];
    lds[k][n] = v.x; lds[k][n+1] = v.y; lds[k][n+2] = v.z; lds[k][n+3] = v.w;
  }
  __syncthreads();
  #pragma unroll
  for (int it = 0; it < 16; ++it) {
    const int f = it*1024 + tid*4;
    const int n = f >> 7, k = f & 127;
    bf16x4 o;
    o.x = f2bf(lds[k][n]);   o.y = f2bf(lds[k+1][n]);
    o.z = f2bf(lds[k+2][n]); o.w = f2bf(lds[k+3][n]);
    *(bf16x4*)&out[f] = o;
  }
}

// ============ K1: fused LN1 + QKVG GEMMs (WT bf16 vector-staged) ============
// y=0: Qp[t][h]=phi(x@Wq) ; y=1: Kp[t][h]+KpT[h][t]=phi(x@Wk)
// y=2: VgT[d][t] = (x@Wv)*sigmoid(x@Wg+bg)
__global__ __launch_bounds__(256) void k_qkvg(const float* __restrict__ tokens,
    const short* __restrict__ WT,
    const float* __restrict__ g1, const float* __restrict__ b1,
    const float* __restrict__ bg,
    short* __restrict__ Qp, short* __restrict__ Kp, short* __restrict__ KpT,
    short* __restrict__ VgT) {
  const int m0 = blockIdx.x * 64;
  const int y = blockIdx.y;
  const int tid = threadIdx.x;
  const int w = tid >> 6, l = tid & 63;
  __shared__ short xs[64][136];
  __shared__ short wsd[128][136];

  // ---- LN1 for this 64-token tile -> xs (bf16)  (verified R4) ----
  {
    const int half = l >> 5;
    const int c4 = (l & 31) * 4;
    const float4 gg = *(const float4*)&g1[c4];
    const float4 bb = *(const float4*)&b1[c4];
    #pragma unroll
    for (int it = 0; it < 8; ++it) {
      const int t = w*16 + it*2 + half;
      const float4 v = *(const float4*)&tokens[(m0+t)*D_ + c4];
      float s = v.x+v.y+v.z+v.w;
      float qq = v.x*v.x+v.y*v.y+v.z*v.z+v.w*v.w;
      #pragma unroll
      for (int off = 1; off < 32; off <<= 1) {
        s += __shfl_xor(s, off); qq += __shfl_xor(qq, off);
      }
      const float mean = s*(1.f/D_);
      const float r2 = rsqrtf(qq*(1.f/D_) - mean*mean + LN_EPS);
      bf16x4 o;
      o.x = f2bf((v.x-mean)*r2*gg.x + bb.x);
      o.y = f2bf((v.y-mean)*r2*gg.y + bb.y);
      o.z = f2bf((v.z-mean)*r2*gg.z + bb.z);
      o.w = f2bf((v.w-mean)*r2*gg.w + bb.w);
      *(bf16x4*)&xs[t][c4] = o;
    }
  }

  // ---- stage pre-transposed W^T bf16, vector (conflict-free) ----
  auto stageW = [&](const short* __restrict__ Wb) {
    for (int v = tid; v < 2048; v += 256) {
      const int n = v >> 4, c8 = (v & 15)*8;
      *(bf16x8*)&wsd[n][c8] = *(const bf16x8*)&Wb[n*D_ + c8];
    }
  };

  const int i = l & 15, q = l >> 4;
  auto gemm = [&](f32x4 (*acc)[2]) {
    #pragma unroll
    for (int kk = 0; kk < 4; ++kk) {
      bf16x8 a[4], bfr[2];
      #pragma unroll
      for (int mt = 0; mt < 4; ++mt) a[mt] = *(const bf16x8*)&xs[mt*16+i][kk*32+q*8];
      #pragma unroll
      for (int nt = 0; nt < 2; ++nt) bfr[nt] = *(const bf16x8*)&wsd[w*32+nt*16+i][kk*32+q*8];
      #pragma unroll
      for (int mt = 0; mt < 4; ++mt)
        #pragma unroll
        for (int nt = 0; nt < 2; ++nt)
          acc[mt][nt] = __builtin_amdgcn_mfma_f32_16x16x32_bf16(a[mt], bfr[nt], acc[mt][nt], 0, 0, 0);
    }
  };

  stageW(WT + (y == 2 ? 2 : y)*D_*D_);
  __syncthreads();
  f32x4 acc[4][2];
  #pragma unroll
  for (int mt = 0; mt < 4; ++mt)
    #pragma unroll
    for (int nt = 0; nt < 2; ++nt) acc[mt][nt] = (f32x4){0.f,0.f,0.f,0.f};
  gemm(acc);

  if (y == 0) {
    #pragma unroll
    for (int mt = 0; mt < 4; ++mt)
      #pragma unroll
      for (int nt = 0; nt < 2; ++nt) {
        const int h = w*32 + nt*16 + i;
        #pragma unroll
        for (int r = 0; r < 4; ++r)
          Qp[(m0 + mt*16 + 4*q + r)*D_ + h] = f2bf(phi_(acc[mt][nt][r]));
      }
  } else if (y == 1) {
    #pragma unroll
    for (int mt = 0; mt < 4; ++mt)
      #pragma unroll
      for (int nt = 0; nt < 2; ++nt) {
        const int h = w*32 + nt*16 + i;
        const int t0 = m0 + mt*16 + 4*q;
        bf16x4 o;
        #pragma unroll
        for (int r = 0; r < 4; ++r) {
          const short bv = f2bf(phi_(acc[mt][nt][r]));
          Kp[(t0+r)*D_ + h] = bv;
          o[r] = bv;
        }
        *(bf16x4*)&KpT[h*NTOK + t0] = o;
      }
  } else {
    __syncthreads();                 // all waves done reading wsd (Wv)
    stageW(WT + 3*D_*D_);            // Wg^T
    __syncthreads();
    f32x4 accg[4][2];
    #pragma unroll
    for (int mt = 0; mt < 4; ++mt)
      #pragma unroll
      for (int nt = 0; nt < 2; ++nt) accg[mt][nt] = (f32x4){0.f,0.f,0.f,0.f};
    gemm(accg);
    #pragma unroll
    for (int mt = 0; mt < 4; ++mt)
      #pragma unroll
      for (int nt = 0; nt < 2; ++nt) {
        const int h = w*32 + nt*16 + i;
        const int t0 = m0 + mt*16 + 4*q;
        const float bgd = bg[h];
        bf16x4 o;
        #pragma unroll
        for (int r = 0; r < 4; ++r) {
          const float gv = 1.f/(1.f + __expf(-(accg[mt][nt][r] + bgd)));
          o[r] = f2bf(acc[mt][nt][r] * gv);
        }
        *(bf16x4*)&VgT[h*NTOK + t0] = o;
      }
  }
}

// ============ K2: per-chunk KV^T[d][h] + Ksum (verified R4) ============
__global__ __launch_bounds__(256) void k_chunkkv(const short* __restrict__ KpT,
    const short* __restrict__ VgT,
    float* __restrict__ KVT, float* __restrict__ Ksum) {
  const int c = blockIdx.x, hh = blockIdx.y;
  const int tid = threadIdx.x;
  const int tb = c*CHUNK;
  __shared__ short vgl[128][72];
  __shared__ short kpl[64][72];
  __shared__ float ksp[64][5];
  #pragma unroll
  for (int u = tid; u < 1024; u += 256) {
    const int d = u >> 3, c8 = (u & 7)*8;
    *(bf16x8*)&vgl[d][c8] = *(const bf16x8*)&VgT[d*NTOK + tb + c8];
  }
  #pragma unroll
  for (int u = tid; u < 512; u += 256) {
    const int h = u >> 3, c8 = (u & 7)*8;
    *(bf16x8*)&kpl[h][c8] = *(const bf16x8*)&KpT[(hh*64+h)*NTOK + tb + c8];
  }
  __syncthreads();
  const int w = tid >> 6, l = tid & 63, i = l & 15, q = l >> 4;
  f32x4 acc[2][4];
  #pragma unroll
  for (int mt = 0; mt < 2; ++mt)
    #pragma unroll
    for (int nt = 0; nt < 4; ++nt) acc[mt][nt] = (f32x4){0.f,0.f,0.f,0.f};
  #pragma unroll
  for (int kk = 0; kk < 2; ++kk) {
    bf16x8 a[2], bb[4];
    #pragma unroll
    for (int mt = 0; mt < 2; ++mt) a[mt] = *(const bf16x8*)&vgl[(2*w+mt)*16+i][kk*32+q*8];
    #pragma unroll
    for (int nt = 0; nt < 4; ++nt) bb[nt] = *(const bf16x8*)&kpl[nt*16+i][kk*32+q*8];
    #pragma unroll
    for (int mt = 0; mt < 2; ++mt)
      #pragma unroll
      for (int nt = 0; nt < 4; ++nt)
        acc[mt][nt] = __builtin_amdgcn_mfma_f32_16x16x32_bf16(a[mt], bb[nt], acc[mt][nt], 0, 0, 0);
  }
  float* KVc = KVT + (size_t)c*16384;
  #pragma unroll
  for (int mt = 0; mt < 2; ++mt)
    #pragma unroll
    for (int nt = 0; nt < 4; ++nt)
      #pragma unroll
      for (int r = 0; r < 4; ++r) {
        const int d = (2*w+mt)*16 + 4*q + r;
        const int h = hh*64 + nt*16 + i;
        KVc[d*128 + h] = acc[mt][nt][r];
      }
  {
    const int h = tid >> 2, part = tid & 3;
    float s = 0.f;
    #pragma unroll
    for (int t = 0; t < 16; ++t) s += bf2f(kpl[h][part*16 + t]);
    ksp[h][part] = s;
  }
  __syncthreads();
  if (tid < 64)
    Ksum[c*128 + hh*64 + tid] = ksp[tid][0]+ksp[tid][1]+ksp[tid][2]+ksp[tid][3];
}

// ============ K3: prefix scan || intra-chunk scores (verified R4) ============
__global__ __launch_bounds__(256) void k_prescore(const float* __restrict__ KVT,
    short* __restrict__ KVTb, float* __restrict__ Ksum,
    const short* __restrict__ Qp, const short* __restrict__ Kp,
    short* __restrict__ A, float* __restrict__ rowsum) {
  const int tid = threadIdx.x;
  if (blockIdx.x < 128) {
    const int b = blockIdx.x >> 6;
    const int e = (blockIdx.x & 63)*256 + tid;
    const size_t base = (size_t)b*NCB*16384 + e;
    float run = 0.f;
    #pragma unroll 8
    for (int c = 0; c < NCB; ++c) {
      const float v = KVT[base + (size_t)c*16384];
      KVTb[base + (size_t)c*16384] = f2bf(run);
      run += v;
    }
    return;
  }
  if (blockIdx.x == 128) {
    const int b = tid >> 7, h = tid & 127;
    float run = 0.f;
    #pragma unroll 8
    for (int c = 0; c < NCB; ++c) {
      const int idx = (b*NCB + c)*128 + h;
      const float v = Ksum[idx];
      Ksum[idx] = run;
      run += v;
    }
    return;
  }
  const int c = blockIdx.x - 129;
  const int tb = c*CHUNK;
  __shared__ short qpl[64][136], kpl[64][136];
  #pragma unroll
  for (int u = tid; u < 1024; u += 256) {
    const int t = u >> 4, c8 = (u & 15)*8;
    *(bf16x8*)&qpl[t][c8] = *(const bf16x8*)&Qp[(tb+t)*D_ + c8];
    *(bf16x8*)&kpl[t][c8] = *(const bf16x8*)&Kp[(tb+t)*D_ + c8];
  }
  __syncthreads();
  const int w = tid >> 6, l = tid & 63, i = l & 15, q = l >> 4;
  f32x4 acc[4];
  #pragma unroll
  for (int nt = 0; nt < 4; ++nt) acc[nt] = (f32x4){0.f,0.f,0.f,0.f};
  #pragma unroll
  for (int kk = 0; kk < 4; ++kk) {
    bf16x8 a = *(const bf16x8*)&qpl[w*16+i][kk*32+q*8];
    for (int nt = 0; nt <= w; ++nt) {
      bf16x8 bb = *(const bf16x8*)&kpl[nt*16+i][kk*32+q*8];
      acc[nt] = __builtin_amdgcn_mfma_f32_16x16x32_bf16(a, bb, acc[nt], 0, 0, 0);
    }
  }
  short* Ac = A + c*4096;
  float rs[4] = {0.f,0.f,0.f,0.f};
  #pragma unroll
  for (int nt = 0; nt < 4; ++nt) {
    #pragma unroll
    for (int r = 0; r < 4; ++r) {
      const int t = w*16 + 4*q + r;
      const int s = nt*16 + i;
      const float v = (nt <= w && s <= t) ? acc[nt][r] : 0.f;
      rs[r] += v;
      Ac[t*64 + s] = f2bf(v);
    }
  }
  #pragma unroll
  for (int r = 0; r < 4; ++r) {
    #pragma unroll
    for (int off = 1; off < 16; off <<= 1) rs[r] += __shfl_xor(rs[r], off);
  }
  if (i == 0) {
    #pragma unroll
    for (int r = 0; r < 4; ++r) rowsum[c*64 + w*16 + 4*q + r] = rs[r];
  }
}

// ============ K4: num/den + attn (verified R4) ============
__global__ __launch_bounds__(256) void k_attnout(const short* __restrict__ Aintra,
    const short* __restrict__ Qp, const short* __restrict__ VgT,
    const short* __restrict__ KVTb, const float* __restrict__ Ksum,
    const float* __restrict__ rowsum, short* __restrict__ attn) {
  const int c = blockIdx.x, dh = blockIdx.y, tid = threadIdx.x;
  const int tb = c*CHUNK;
  __shared__ short at[64][200], bt[64][200];
  __shared__ float ksl[128], dpart[64][4], denl[64];
  const short* Ac = Aintra + c*4096;
  #pragma unroll
  for (int u = tid; u < 512; u += 256) {
    const int t = u >> 3, c8 = (u & 7)*8;
    *(bf16x8*)&at[t][c8] = *(const bf16x8*)&Ac[t*64 + c8];
  }
  #pragma unroll
  for (int u = tid; u < 1024; u += 256) {
    const int t = u >> 4, c8 = (u & 15)*8;
    *(bf16x8*)&at[t][64 + c8] = *(const bf16x8*)&Qp[(tb+t)*D_ + c8];
  }
  #pragma unroll
  for (int u = tid; u < 512; u += 256) {
    const int dd = u >> 3, c8 = (u & 7)*8;
    *(bf16x8*)&bt[dd][c8] = *(const bf16x8*)&VgT[(dh*64+dd)*NTOK + tb + c8];
  }
  #pragma unroll
  for (int u = tid; u < 1024; u += 256) {
    const int dd = u >> 4, c8 = (u & 15)*8;
    *(bf16x8*)&bt[dd][64 + c8] = *(const bf16x8*)&KVTb[(size_t)c*16384 + (dh*64+dd)*128 + c8];
  }
  if (tid < 128) ksl[tid] = Ksum[c*128 + tid];
  __syncthreads();
  {
    const int t = tid >> 2, part = tid & 3;
    float dot = 0.f;
    #pragma unroll
    for (int h = 0; h < 32; ++h) dot += bf2f(at[t][64 + part*32 + h]) * ksl[part*32 + h];
    dpart[t][part] = dot;
  }
  __syncthreads();
  if (tid < 64)
    denl[tid] = fmaxf(rowsum[c*64 + tid] + dpart[tid][0]+dpart[tid][1]+dpart[tid][2]+dpart[tid][3], EPS_ATTN);
  __syncthreads();
  const int w = tid >> 6, l = tid & 63, i = l & 15, q = l >> 4;
  f32x4 acc[4];
  #pragma unroll
  for (int nt = 0; nt < 4; ++nt) acc[nt] = (f32x4){0.f,0.f,0.f,0.f};
  #pragma unroll
  for (int kk = 0; kk < 6; ++kk) {
    bf16x8 a = *(const bf16x8*)&at[w*16+i][kk*32+q*8];
    #pragma unroll
    for (int nt = 0; nt < 4; ++nt) {
      bf16x8 bb = *(const bf16x8*)&bt[nt*16+i][kk*32+q*8];
      acc[nt] = __builtin_amdgcn_mfma_f32_16x16x32_bf16(a, bb, acc[nt], 0, 0, 0);
    }
  }
  #pragma unroll
  for (int r = 0; r < 4; ++r) {
    const int t = w*16 + 4*q + r;
    const float inv = 1.f / denl[t];
    #pragma unroll
    for (int nt = 0; nt < 4; ++nt)
      attn[(size_t)(tb+t)*D_ + dh*64 + nt*16 + i] = f2bf(acc[nt][r] * inv);
  }
}

// ============ K5: out = LN2(tokens + 0.1*(attn@Wo)), WoT bf16 vector-staged ============
__global__ __launch_bounds__(256) void k_outln2(const short* __restrict__ attn,
    const short* __restrict__ WoT, const float* __restrict__ tokens,
    const float* __restrict__ g2, const float* __restrict__ b2,
    float* __restrict__ out) {
  const int m0 = blockIdx.x*32, tid = threadIdx.x;
  __shared__ short al[32][136], wl[128][136];
  __shared__ float tl[32][132];
  __shared__ float suml[32][2], ssql[32][2];
  __shared__ float meanl[32], rstdl[32];
  __shared__ float gl[128], bl2[128];
  #pragma unroll
  for (int u = tid; u < 512; u += 256) {
    const int t = u >> 4, c8 = (u & 15)*8;
    *(bf16x8*)&al[t][c8] = *(const bf16x8*)&attn[(m0+t)*D_ + c8];
  }
  #pragma unroll
  for (int u = tid; u < 2048; u += 256) {
    const int n = u >> 4, c8 = (u & 15)*8;
    *(bf16x8*)&wl[n][c8] = *(const bf16x8*)&WoT[n*D_ + c8];
  }
  #pragma unroll
  for (int u = tid; u < 1024; u += 256) {
    const int t = u >> 5, c4 = (u & 31)*4;
    *(float4*)&tl[t][c4] = *(const float4*)&tokens[(m0+t)*D_ + c4];
  }
  if (tid < 128) { gl[tid] = g2[tid]; bl2[tid] = b2[tid]; }
  __syncthreads();
  const int w = tid >> 6, l = tid & 63, i = l & 15, q = l >> 4;
  const int mt = w >> 1, nh = w & 1;
  f32x4 acc[4];
  #pragma unroll
  for (int j = 0; j < 4; ++j) acc[j] = (f32x4){0.f,0.f,0.f,0.f};
  #pragma unroll
  for (int kk = 0; kk < 4; ++kk) {
    bf16x8 a = *(const bf16x8*)&al[mt*16+i][kk*32+q*8];
    #pragma unroll
    for (int j = 0; j < 4; ++j) {
      bf16x8 bb = *(const bf16x8*)&wl[(nh*4+j)*16+i][kk*32+q*8];
      acc[j] = __builtin_amdgcn_mfma_f32_16x16x32_bf16(a, bb, acc[j], 0, 0, 0);
    }
  }
  float p[4][4], ps[4], qs[4];
  #pragma unroll
  for (int r = 0; r < 4; ++r) {
    const int t = mt*16 + 4*q + r;
    ps[r] = 0.f; qs[r] = 0.f;
    #pragma unroll
    for (int j = 0; j < 4; ++j) {
      const int col = nh*64 + j*16 + i;
      const float v = tl[t][col] + 0.1f*acc[j][r];
      p[r][j] = v; ps[r] += v; qs[r] += v*v;
    }
  }
  #pragma unroll
  for (int r = 0; r < 4; ++r) {
    #pragma unroll
    for (int off = 1; off < 16; off <<= 1) {
      ps[r] += __shfl_xor(ps[r], off);
      qs[r] += __shfl_xor(qs[r], off);
    }
  }
  if (i == 0) {
    #pragma unroll
    for (int r = 0; r < 4; ++r) {
      suml[mt*16+4*q+r][nh] = ps[r];
      ssql[mt*16+4*q+r][nh] = qs[r];
    }
  }
  __syncthreads();
  if (tid < 32) {
    const float s = suml[tid][0] + suml[tid][1];
    const float qq = ssql[tid][0] + ssql[tid][1];
    const float mean = s*(1.f/D_);
    meanl[tid] = mean;
    rstdl[tid] = rsqrtf(qq*(1.f/D_) - mean*mean + LN_EPS);
  }
  __syncthreads();
  #pragma unroll
  for (int r = 0; r < 4; ++r) {
    const int t = mt*16 + 4*q + r;
    const float mean = meanl[t], rr = rstdl[t];
    #pragma unroll
    for (int j = 0; j < 4; ++j) {
      const int col = nh*64 + j*16 + i;
      out[(m0+t)*D_ + col] = (p[r][j]-mean)*rr*gl[col] + bl2[col];
    }
  }
}

extern "C" void kernel_launch(void* const* d_in, const int* in_sizes, int n_in,
                              void* d_out, int out_size, void* d_ws, size_t ws_size,
                              hipStream_t stream) {
  const float* tokens = (const float*)d_in[0];
  const float* Wq = (const float*)d_in[1];
  const float* Wk = (const float*)d_in[2];
  const float* Wv = (const float*)d_in[3];
  const float* Wg = (const float*)d_in[4];
  const float* bg = (const float*)d_in[5];
  const float* Wo = (const float*)d_in[6];
  const float* g1 = (const float*)d_in[7];
  const float* b1 = (const float*)d_in[8];
  const float* g2 = (const float*)d_in[9];
  const float* b2 = (const float*)d_in[10];

  char* base = (char*)d_ws;
  short* Qp     = (short*)(base);                        // 2MB
  short* Kp     = (short*)(base + (2u<<20));             // 2MB
  short* KpT    = (short*)(base + (4u<<20));             // 2MB
  short* VgT    = (short*)(base + (6u<<20));             // 2MB
  short* attn   = (short*)(base + (8u<<20));             // 2MB
  short* KVTb   = (short*)(base + (10u<<20));            // 4MB
  short* Aintra = (short*)(base + (14u<<20));            // 1MB
  short* WT     = (short*)(base + (15u<<20));            // 160KB (5 mats)
  float* rowsum = (float*)(base + (15u<<20) + (256u<<10)); // 32KB
  float* Ksum   = (float*)(base + (15u<<20) + (512u<<10)); // 64KB
  float* KVT    = (float*)(base + (16u<<20));            // 8MB

  short* WoT = WT + 4*D_*D_;

  k_wprep<<<5, 256, 0, stream>>>(Wq, Wk, Wv, Wg, Wo, WT);
  k_qkvg<<<dim3(NTOK/64, 3), 256, 0, stream>>>(tokens, WT, g1, b1, bg,
                                               Qp, Kp, KpT, VgT);
  k_chunkkv<<<dim3(NCH, 2), 256, 0, stream>>>(KpT, VgT, KVT, Ksum);
  k_prescore<<<257, 256, 0, stream>>>(KVT, KVTb, Ksum, Qp, Kp, Aintra, rowsum);
  k_attnout<<<dim3(NCH, 2), 256, 0, stream>>>(Aintra, Qp, VgT, KVTb, Ksum, rowsum, attn);
  k_outln2<<<NTOK/32, 256, 0, stream>>>(attn, WoT, tokens, g2, b2, (float*)d_out);
}

// Round 10
// 114.207 us; speedup vs baseline: 2.3489x; 1.0222x over previous
//
#include <hip/hip_runtime.h>
#include <math.h>

#define T_ 4096
#define D_ 128
#define NTOK 8192
#define CHUNK 64
#define NCB 64        // chunks per batch
#define NCH 128       // total chunks
#define LN_EPS 1e-5f
#define EPS_ATTN 1e-6f

typedef __attribute__((ext_vector_type(8))) short bf16x8;
typedef __attribute__((ext_vector_type(4))) short bf16x4;
typedef __attribute__((ext_vector_type(2))) short bf16x2;
typedef __attribute__((ext_vector_type(4))) float f32x4;

__device__ inline short f2bf(float f) {
  unsigned u = __builtin_bit_cast(unsigned, f);
  u += 0x7fffu + ((u >> 16) & 1u);
  return (short)(u >> 16);
}
__device__ inline float bf2f(short s) {
  unsigned u = ((unsigned)(unsigned short)s) << 16;
  return __builtin_bit_cast(float, u);
}
__device__ inline float phi_(float x) { return x > 0.f ? x + 1.f : __expf(x); }

// ============ K0: weights fp32 [k][n] -> bf16 [n][k] once (5 mats, verified R3) ============
__global__ __launch_bounds__(256) void k_wprep(const float* __restrict__ Wq,
    const float* __restrict__ Wk, const float* __restrict__ Wv,
    const float* __restrict__ Wg, const float* __restrict__ Wo,
    short* __restrict__ WT) {
  const float* W = blockIdx.x==0?Wq: blockIdx.x==1?Wk: blockIdx.x==2?Wv: blockIdx.x==3?Wg:Wo;
  short* out = WT + blockIdx.x*D_*D_;
  __shared__ float lds[128][132];
  const int tid = threadIdx.x;
  #pragma unroll
  for (int it = 0; it < 16; ++it) {
    const int f = it*1024 + tid*4;
    const int k = f >> 7, n = f & 127;
    const float4 v = *(const float4*)&W[f];
    lds[k][n] = v.x; lds[k][n+1] = v.y; lds[k][n+2] = v.z; lds[k][n+3] = v.w;
  }
  __syncthreads();
  #pragma unroll
  for (int it = 0; it < 16; ++it) {
    const int f = it*1024 + tid*4;
    const int n = f >> 7, k = f & 127;
    bf16x4 o;
    o.x = f2bf(lds[k][n]);   o.y = f2bf(lds[k+1][n]);
    o.z = f2bf(lds[k+2][n]); o.w = f2bf(lds[k+3][n]);
    *(bf16x4*)&out[f] = o;
  }
}

// ============ K1: fused LN1 + QKVG GEMMs, 32-token tiles (768 blocks) ============
// y=0: Qp=phi(x@Wq) ; y=1: Kp+KpT=phi(x@Wk) ; y=2: VgT=(x@Wv)*sigmoid(x@Wg+bg)
__global__ __launch_bounds__(256) void k_qkvg(const float* __restrict__ tokens,
    const short* __restrict__ WT,
    const float* __restrict__ g1, const float* __restrict__ b1,
    const float* __restrict__ bg,
    short* __restrict__ Qp, short* __restrict__ Kp, short* __restrict__ KpT,
    short* __restrict__ VgT) {
  const int m0 = blockIdx.x * 32;
  const int y = blockIdx.y;
  const int tid = threadIdx.x;
  const int w = tid >> 6, l = tid & 63;
  __shared__ short xs[32][136];
  __shared__ short wsd[128][136];

  // ---- LN1 for 32 tokens: wave w handles tokens w*8..w*8+7, 2 floats/lane ----
  {
    const float2 gg = *(const float2*)&g1[l*2];
    const float2 bb = *(const float2*)&b1[l*2];
    float2 tv[8];
    #pragma unroll
    for (int it = 0; it < 8; ++it)
      tv[it] = *(const float2*)&tokens[(m0 + w*8 + it)*D_ + l*2];
    #pragma unroll
    for (int it = 0; it < 8; ++it) {
      const float2 v = tv[it];
      float s = v.x + v.y, qq = v.x*v.x + v.y*v.y;
      #pragma unroll
      for (int off = 1; off < 64; off <<= 1) {
        s += __shfl_xor(s, off); qq += __shfl_xor(qq, off);
      }
      const float mean = s*(1.f/D_);
      const float r2 = rsqrtf(qq*(1.f/D_) - mean*mean + LN_EPS);
      bf16x2 o;
      o.x = f2bf((v.x-mean)*r2*gg.x + bb.x);
      o.y = f2bf((v.y-mean)*r2*gg.y + bb.y);
      *(bf16x2*)&xs[w*8 + it][l*2] = o;
    }
  }

  auto stageW = [&](const short* __restrict__ Wb) {
    for (int v = tid; v < 2048; v += 256) {
      const int n = v >> 4, c8 = (v & 15)*8;
      *(bf16x8*)&wsd[n][c8] = *(const bf16x8*)&Wb[n*D_ + c8];
    }
  };

  const int i = l & 15, q = l >> 4;
  auto gemm = [&](f32x4 (*acc)[2]) {
    #pragma unroll
    for (int kk = 0; kk < 4; ++kk) {
      bf16x8 a[2], bfr[2];
      #pragma unroll
      for (int mt = 0; mt < 2; ++mt) a[mt] = *(const bf16x8*)&xs[mt*16+i][kk*32+q*8];
      #pragma unroll
      for (int nt = 0; nt < 2; ++nt) bfr[nt] = *(const bf16x8*)&wsd[w*32+nt*16+i][kk*32+q*8];
      #pragma unroll
      for (int mt = 0; mt < 2; ++mt)
        #pragma unroll
        for (int nt = 0; nt < 2; ++nt)
          acc[mt][nt] = __builtin_amdgcn_mfma_f32_16x16x32_bf16(a[mt], bfr[nt], acc[mt][nt], 0, 0, 0);
    }
  };

  stageW(WT + (y == 2 ? 2 : y)*D_*D_);
  __syncthreads();
  f32x4 acc[2][2];
  #pragma unroll
  for (int mt = 0; mt < 2; ++mt)
    #pragma unroll
    for (int nt = 0; nt < 2; ++nt) acc[mt][nt] = (f32x4){0.f,0.f,0.f,0.f};
  gemm(acc);

  if (y == 0) {
    #pragma unroll
    for (int mt = 0; mt < 2; ++mt)
      #pragma unroll
      for (int nt = 0; nt < 2; ++nt) {
        const int h = w*32 + nt*16 + i;
        #pragma unroll
        for (int r = 0; r < 4; ++r)
          Qp[(m0 + mt*16 + 4*q + r)*D_ + h] = f2bf(phi_(acc[mt][nt][r]));
      }
  } else if (y == 1) {
    #pragma unroll
    for (int mt = 0; mt < 2; ++mt)
      #pragma unroll
      for (int nt = 0; nt < 2; ++nt) {
        const int h = w*32 + nt*16 + i;
        const int t0 = m0 + mt*16 + 4*q;
        bf16x4 o;
        #pragma unroll
        for (int r = 0; r < 4; ++r) {
          const short bv = f2bf(phi_(acc[mt][nt][r]));
          Kp[(t0+r)*D_ + h] = bv;
          o[r] = bv;
        }
        *(bf16x4*)&KpT[h*NTOK + t0] = o;
      }
  } else {
    __syncthreads();
    stageW(WT + 3*D_*D_);            // Wg^T
    __syncthreads();
    f32x4 accg[2][2];
    #pragma unroll
    for (int mt = 0; mt < 2; ++mt)
      #pragma unroll
      for (int nt = 0; nt < 2; ++nt) accg[mt][nt] = (f32x4){0.f,0.f,0.f,0.f};
    gemm(accg);
    #pragma unroll
    for (int mt = 0; mt < 2; ++mt)
      #pragma unroll
      for (int nt = 0; nt < 2; ++nt) {
        const int h = w*32 + nt*16 + i;
        const int t0 = m0 + mt*16 + 4*q;
        const float bgd = bg[h];
        bf16x4 o;
        #pragma unroll
        for (int r = 0; r < 4; ++r) {
          const float gv = 1.f/(1.f + __expf(-(accg[mt][nt][r] + bgd)));
          o[r] = f2bf(acc[mt][nt][r] * gv);
        }
        *(bf16x4*)&VgT[h*NTOK + t0] = o;
      }
  }
}

// ============ K2: per-chunk KV^T quarters + Ksum (512 blocks, verified R8 shape) ============
__global__ __launch_bounds__(256) void k_chunkkv(const short* __restrict__ KpT,
    const short* __restrict__ VgT,
    float* __restrict__ KVT, float* __restrict__ Ksum) {
  const int c = blockIdx.x, hh = blockIdx.y, dh = blockIdx.z;
  const int tid = threadIdx.x;
  const int tb = c*CHUNK;
  __shared__ short vgl[64][72];
  __shared__ short kpl[64][72];
  __shared__ float ksp[64][5];
  for (int u = tid; u < 512; u += 256) {
    const int dd = u >> 3, c8 = (u & 7)*8;
    *(bf16x8*)&vgl[dd][c8] = *(const bf16x8*)&VgT[(dh*64+dd)*NTOK + tb + c8];
    *(bf16x8*)&kpl[dd][c8] = *(const bf16x8*)&KpT[(hh*64+dd)*NTOK + tb + c8];
  }
  __syncthreads();
  const int w = tid >> 6, l = tid & 63, i = l & 15, q = l >> 4;
  f32x4 acc[4];
  #pragma unroll
  for (int nt = 0; nt < 4; ++nt) acc[nt] = (f32x4){0.f,0.f,0.f,0.f};
  #pragma unroll
  for (int kk = 0; kk < 2; ++kk) {
    bf16x8 a = *(const bf16x8*)&vgl[w*16+i][kk*32+q*8];
    #pragma unroll
    for (int nt = 0; nt < 4; ++nt) {
      bf16x8 bb = *(const bf16x8*)&kpl[nt*16+i][kk*32+q*8];
      acc[nt] = __builtin_amdgcn_mfma_f32_16x16x32_bf16(a, bb, acc[nt], 0, 0, 0);
    }
  }
  float* KVc = KVT + (size_t)c*16384;
  #pragma unroll
  for (int nt = 0; nt < 4; ++nt)
    #pragma unroll
    for (int r = 0; r < 4; ++r) {
      const int d = dh*64 + w*16 + 4*q + r;
      const int h = hh*64 + nt*16 + i;
      KVc[d*D_ + h] = acc[nt][r];
    }
  if (dh == 0) {
    const int h = tid >> 2, part = tid & 3;
    float s = 0.f;
    #pragma unroll
    for (int t = 0; t < 16; ++t) s += bf2f(kpl[h][part*16 + t]);
    ksp[h][part] = s;
    __syncthreads();
    if (tid < 64)
      Ksum[c*D_ + hh*64 + tid] = ksp[tid][0]+ksp[tid][1]+ksp[tid][2]+ksp[tid][3];
  }
}

// ============ K3: prefix scan || intra-chunk scores (verified R4/R9) ============
__global__ __launch_bounds__(256) void k_prescore(const float* __restrict__ KVT,
    short* __restrict__ KVTb, float* __restrict__ Ksum,
    const short* __restrict__ Qp, const short* __restrict__ Kp,
    short* __restrict__ A, float* __restrict__ rowsum) {
  const int tid = threadIdx.x;
  if (blockIdx.x < 128) {
    const int b = blockIdx.x >> 6;
    const int e = (blockIdx.x & 63)*256 + tid;
    const size_t base = (size_t)b*NCB*16384 + e;
    float run = 0.f;
    #pragma unroll 8
    for (int c = 0; c < NCB; ++c) {
      const float v = KVT[base + (size_t)c*16384];
      KVTb[base + (size_t)c*16384] = f2bf(run);
      run += v;
    }
    return;
  }
  if (blockIdx.x == 128) {
    const int b = tid >> 7, h = tid & 127;
    float run = 0.f;
    #pragma unroll 8
    for (int c = 0; c < NCB; ++c) {
      const int idx = (b*NCB + c)*128 + h;
      const float v = Ksum[idx];
      Ksum[idx] = run;
      run += v;
    }
    return;
  }
  const int c = blockIdx.x - 129;
  const int tb = c*CHUNK;
  __shared__ short qpl[64][136], kpl[64][136];
  #pragma unroll
  for (int u = tid; u < 1024; u += 256) {
    const int t = u >> 4, c8 = (u & 15)*8;
    *(bf16x8*)&qpl[t][c8] = *(const bf16x8*)&Qp[(tb+t)*D_ + c8];
    *(bf16x8*)&kpl[t][c8] = *(const bf16x8*)&Kp[(tb+t)*D_ + c8];
  }
  __syncthreads();
  const int w = tid >> 6, l = tid & 63, i = l & 15, q = l >> 4;
  f32x4 acc[4];
  #pragma unroll
  for (int nt = 0; nt < 4; ++nt) acc[nt] = (f32x4){0.f,0.f,0.f,0.f};
  #pragma unroll
  for (int kk = 0; kk < 4; ++kk) {
    bf16x8 a = *(const bf16x8*)&qpl[w*16+i][kk*32+q*8];
    for (int nt = 0; nt <= w; ++nt) {
      bf16x8 bb = *(const bf16x8*)&kpl[nt*16+i][kk*32+q*8];
      acc[nt] = __builtin_amdgcn_mfma_f32_16x16x32_bf16(a, bb, acc[nt], 0, 0, 0);
    }
  }
  short* Ac = A + c*4096;
  float rs[4] = {0.f,0.f,0.f,0.f};
  #pragma unroll
  for (int nt = 0; nt < 4; ++nt) {
    #pragma unroll
    for (int r = 0; r < 4; ++r) {
      const int t = w*16 + 4*q + r;
      const int s = nt*16 + i;
      const float v = (nt <= w && s <= t) ? acc[nt][r] : 0.f;
      rs[r] += v;
      Ac[t*64 + s] = f2bf(v);
    }
  }
  #pragma unroll
  for (int r = 0; r < 4; ++r) {
    #pragma unroll
    for (int off = 1; off < 16; off <<= 1) rs[r] += __shfl_xor(rs[r], off);
  }
  if (i == 0) {
    #pragma unroll
    for (int r = 0; r < 4; ++r) rowsum[c*64 + w*16 + 4*q + r] = rs[r];
  }
}

// ============ K4: num/den + attn, d-quarters (512 blocks) ============
__global__ __launch_bounds__(256) void k_attnout(const short* __restrict__ Aintra,
    const short* __restrict__ Qp, const short* __restrict__ VgT,
    const short* __restrict__ KVTb, const float* __restrict__ Ksum,
    const float* __restrict__ rowsum, short* __restrict__ attn) {
  const int c = blockIdx.x, dq = blockIdx.y, tid = threadIdx.x;
  const int tb = c*CHUNK;
  __shared__ short at[64][200], bt[32][200];
  __shared__ float ksl[128], dpart[64][4], denl[64];
  const short* Ac = Aintra + c*4096;
  #pragma unroll
  for (int u = tid; u < 512; u += 256) {
    const int t = u >> 3, c8 = (u & 7)*8;
    *(bf16x8*)&at[t][c8] = *(const bf16x8*)&Ac[t*64 + c8];
  }
  #pragma unroll
  for (int u = tid; u < 1024; u += 256) {
    const int t = u >> 4, c8 = (u & 15)*8;
    *(bf16x8*)&at[t][64 + c8] = *(const bf16x8*)&Qp[(tb+t)*D_ + c8];
  }
  for (int u = tid; u < 256; u += 256) {
    const int dd = u >> 3, c8 = (u & 7)*8;
    *(bf16x8*)&bt[dd][c8] = *(const bf16x8*)&VgT[(dq*32+dd)*NTOK + tb + c8];
  }
  #pragma unroll
  for (int u = tid; u < 512; u += 256) {
    const int dd = u >> 4, c8 = (u & 15)*8;
    *(bf16x8*)&bt[dd][64 + c8] = *(const bf16x8*)&KVTb[(size_t)c*16384 + (dq*32+dd)*D_ + c8];
  }
  if (tid < 128) ksl[tid] = Ksum[c*128 + tid];
  __syncthreads();
  {
    const int t = tid >> 2, part = tid & 3;
    float dot = 0.f;
    #pragma unroll
    for (int h = 0; h < 32; ++h) dot += bf2f(at[t][64 + part*32 + h]) * ksl[part*32 + h];
    dpart[t][part] = dot;
  }
  __syncthreads();
  if (tid < 64)
    denl[tid] = fmaxf(rowsum[c*64 + tid] + dpart[tid][0]+dpart[tid][1]+dpart[tid][2]+dpart[tid][3], EPS_ATTN);
  __syncthreads();
  const int w = tid >> 6, l = tid & 63, i = l & 15, q = l >> 4;
  f32x4 acc[2];
  #pragma unroll
  for (int nt = 0; nt < 2; ++nt) acc[nt] = (f32x4){0.f,0.f,0.f,0.f};
  #pragma unroll
  for (int kk = 0; kk < 6; ++kk) {
    bf16x8 a = *(const bf16x8*)&at[w*16+i][kk*32+q*8];
    #pragma unroll
    for (int nt = 0; nt < 2; ++nt) {
      bf16x8 bb = *(const bf16x8*)&bt[nt*16+i][kk*32+q*8];
      acc[nt] = __builtin_amdgcn_mfma_f32_16x16x32_bf16(a, bb, acc[nt], 0, 0, 0);
    }
  }
  #pragma unroll
  for (int r = 0; r < 4; ++r) {
    const int t = w*16 + 4*q + r;
    const float inv = 1.f / denl[t];
    #pragma unroll
    for (int nt = 0; nt < 2; ++nt)
      attn[(size_t)(tb+t)*D_ + dq*32 + nt*16 + i] = f2bf(acc[nt][r] * inv);
  }
}

// ============ K5: out = LN2(tokens + 0.1*(attn@Wo)), 16-token tiles (512 blocks) ============
__global__ __launch_bounds__(256) void k_outln2(const short* __restrict__ attn,
    const short* __restrict__ WoT, const float* __restrict__ tokens,
    const float* __restrict__ g2, const float* __restrict__ b2,
    float* __restrict__ out) {
  const int m0 = blockIdx.x*16, tid = threadIdx.x;
  __shared__ short al[16][136], wl[128][136];
  __shared__ float tl[16][132];
  __shared__ float suml[16][4], ssql[16][4];
  __shared__ float meanl[16], rstdl[16];
  __shared__ float gl[128], bl2[128];
  for (int u = tid; u < 256; u += 256) {
    const int t = u >> 4, c8 = (u & 15)*8;
    *(bf16x8*)&al[t][c8] = *(const bf16x8*)&attn[(m0+t)*D_ + c8];
  }
  #pragma unroll
  for (int u = tid; u < 2048; u += 256) {
    const int n = u >> 4, c8 = (u & 15)*8;
    *(bf16x8*)&wl[n][c8] = *(const bf16x8*)&WoT[n*D_ + c8];
  }
  #pragma unroll
  for (int u = tid; u < 512; u += 256) {
    const int t = u >> 5, c4 = (u & 31)*4;
    *(float4*)&tl[t][c4] = *(const float4*)&tokens[(m0+t)*D_ + c4];
  }
  if (tid < 128) { gl[tid] = g2[tid]; bl2[tid] = b2[tid]; }
  __syncthreads();
  const int w = tid >> 6, l = tid & 63, i = l & 15, q = l >> 4;
  f32x4 acc[2];
  #pragma unroll
  for (int j = 0; j < 2; ++j) acc[j] = (f32x4){0.f,0.f,0.f,0.f};
  #pragma unroll
  for (int kk = 0; kk < 4; ++kk) {
    bf16x8 a = *(const bf16x8*)&al[i][kk*32+q*8];
    #pragma unroll
    for (int j = 0; j < 2; ++j) {
      bf16x8 bb = *(const bf16x8*)&wl[(w*2+j)*16+i][kk*32+q*8];
      acc[j] = __builtin_amdgcn_mfma_f32_16x16x32_bf16(a, bb, acc[j], 0, 0, 0);
    }
  }
  float p[4][2], ps[4], qs[4];
  #pragma unroll
  for (int r = 0; r < 4; ++r) {
    const int t = 4*q + r;
    ps[r] = 0.f; qs[r] = 0.f;
    #pragma unroll
    for (int j = 0; j < 2; ++j) {
      const int col = w*32 + j*16 + i;
      const float v = tl[t][col] + 0.1f*acc[j][r];
      p[r][j] = v; ps[r] += v; qs[r] += v*v;
    }
  }
  #pragma unroll
  for (int r = 0; r < 4; ++r) {
    #pragma unroll
    for (int off = 1; off < 16; off <<= 1) {
      ps[r] += __shfl_xor(ps[r], off);
      qs[r] += __shfl_xor(qs[r], off);
    }
  }
  if (i == 0) {
    #pragma unroll
    for (int r = 0; r < 4; ++r) {
      suml[4*q+r][w] = ps[r];
      ssql[4*q+r][w] = qs[r];
    }
  }
  __syncthreads();
  if (tid < 16) {
    const float s = suml[tid][0]+suml[tid][1]+suml[tid][2]+suml[tid][3];
    const float qq = ssql[tid][0]+ssql[tid][1]+ssql[tid][2]+ssql[tid][3];
    const float mean = s*(1.f/D_);
    meanl[tid] = mean;
    rstdl[tid] = rsqrtf(qq*(1.f/D_) - mean*mean + LN_EPS);
  }
  __syncthreads();
  #pragma unroll
  for (int r = 0; r < 4; ++r) {
    const int t = 4*q + r;
    const float mean = meanl[t], rr = rstdl[t];
    #pragma unroll
    for (int j = 0; j < 2; ++j) {
      const int col = w*32 + j*16 + i;
      out[(m0+t)*D_ + col] = (p[r][j]-mean)*rr*gl[col] + bl2[col];
    }
  }
}

extern "C" void kernel_launch(void* const* d_in, const int* in_sizes, int n_in,
                              void* d_out, int out_size, void* d_ws, size_t ws_size,
                              hipStream_t stream) {
  const float* tokens = (const float*)d_in[0];
  const float* Wq = (const float*)d_in[1];
  const float* Wk = (const float*)d_in[2];
  const float* Wv = (const float*)d_in[3];
  const float* Wg = (const float*)d_in[4];
  const float* bg = (const float*)d_in[5];
  const float* Wo = (const float*)d_in[6];
  const float* g1 = (const float*)d_in[7];
  const float* b1 = (const float*)d_in[8];
  const float* g2 = (const float*)d_in[9];
  const float* b2 = (const float*)d_in[10];

  char* base = (char*)d_ws;
  short* Qp     = (short*)(base);                        // 2MB
  short* Kp     = (short*)(base + (2u<<20));             // 2MB
  short* KpT    = (short*)(base + (4u<<20));             // 2MB
  short* VgT    = (short*)(base + (6u<<20));             // 2MB
  short* attn   = (short*)(base + (8u<<20));             // 2MB
  short* KVTb   = (short*)(base + (10u<<20));            // 4MB
  short* Aintra = (short*)(base + (14u<<20));            // 1MB
  short* WT     = (short*)(base + (15u<<20));            // 160KB (5 mats)
  float* rowsum = (float*)(base + (15u<<20) + (256u<<10)); // 32KB
  float* Ksum   = (float*)(base + (15u<<20) + (512u<<10)); // 64KB
  float* KVT    = (float*)(base + (16u<<20));            // 8MB

  short* WoT = WT + 4*D_*D_;

  k_wprep<<<5, 256, 0, stream>>>(Wq, Wk, Wv, Wg, Wo, WT);
  k_qkvg<<<dim3(NTOK/32, 3), 256, 0, stream>>>(tokens, WT, g1, b1, bg,
                                               Qp, Kp, KpT, VgT);
  k_chunkkv<<<dim3(NCH, 2, 2), 256, 0, stream>>>(KpT, VgT, KVT, Ksum);
  k_prescore<<<257, 256, 0, stream>>>(KVT, KVTb, Ksum, Qp, Kp, Aintra, rowsum);
  k_attnout<<<dim3(NCH, 4), 256, 0, stream>>>(Aintra, Qp, VgT, KVTb, Ksum, rowsum, attn);
  k_outln2<<<NTOK/16, 256, 0, stream>>>(attn, WoT, tokens, g2, b2, (float*)d_out);
}